// Round 6
// baseline (49.910 us; speedup 1.0000x reference)
//
#include <hip/hip_runtime.h>

// Problem constants (x: [4, 64, 64, 64] fp32)
#define Bn 4
#define Cn 64
#define HWn 4096
#define KK 8   // Taylor terms: |m_i*m_j| <= ~0.31 -> remainder 0.31^8/8! ~ 2e-9
#define NBLK 256

// Single kernel, grid 256 x 256 (all blocks co-resident on 256 CUs).
// Phase A: block g = (b, pixel-slice): chunk-load x (64ch x 64px), compute
//   m slice, denominator partials pmpart[g][k], numerator partials
//   papart[g][c][k] for all 64 channels.
// Device-scope spin barrier (cnt zeroed by a 4B memset node each call).
// Phase B: block g = (b, c): merge 64 partials, Horner-eval, write out row.
__global__ __launch_bounds__(256) void fused_all(const float* __restrict__ x,
                                                 float* __restrict__ out,
                                                 unsigned* __restrict__ cnt,
                                                 float* __restrict__ m,
                                                 float* __restrict__ pmpart,
                                                 float* __restrict__ papart) {
    const float inv_fact[KK] = {1.f, 1.f, 0.5f, 1.f / 6.f, 1.f / 24.f,
                                1.f / 120.f, 1.f / 720.f, 1.f / 5040.f};
    const int g = blockIdx.x;
    const int t = threadIdx.x, lane = t & 63, w = t >> 6;

    __shared__ float xs[64][65];      // [channel][pixel], padded
    __shared__ float redA[4][64];
    __shared__ float marr[64];
    __shared__ float red2[4][64][9];  // [quarter][channel][k], padded
    __shared__ float coef[2 * KK];

    // ---------------- Phase A ----------------
    {
        const int b = g >> 6;
        const int i0 = (g & 63) * 64;
        const float* xb = x + ((size_t)(b * Cn + w * 16)) * HWn + i0 + lane;
        float s = 0.f;
#pragma unroll
        for (int cc = 0; cc < 16; ++cc) {
            float v = xb[(size_t)cc * HWn];
            xs[w * 16 + cc][lane] = v;
            s += v;
        }
        redA[w][lane] = s;
        __syncthreads();

        if (w == 0) {
            float mv = (redA[0][lane] + redA[1][lane] + redA[2][lane] + redA[3][lane])
                       * (1.0f / Cn);
            m[b * HWn + i0 + lane] = mv;
            marr[lane] = mv;
            float q[KK];
            q[1] = mv;
#pragma unroll
            for (int k = 2; k < KK; ++k) q[k] = q[k - 1] * mv;
#pragma unroll
            for (int k = 1; k < KK; ++k) {
                float v = q[k];
#pragma unroll
                for (int o = 32; o; o >>= 1) v += __shfl_xor(v, o, 64);
                if (lane == 0) pmpart[g * KK + k] = v;   // raw sums
            }
        }
        __syncthreads();

        const int c = lane, qd = w;
        float pa[KK];
#pragma unroll
        for (int k = 0; k < KK; ++k) pa[k] = 0.f;
#pragma unroll
        for (int pp = 0; pp < 16; ++pp) {
            int pix = qd * 16 + pp;
            float mval = marr[pix];   // wave-broadcast
            float p = xs[c][pix];     // 2 lanes/bank via pad -> free
            pa[0] += p;
#pragma unroll
            for (int k = 1; k < KK; ++k) { p *= mval; pa[k] += p; }
        }
#pragma unroll
        for (int k = 0; k < KK; ++k) red2[qd][c][k] = pa[k];
        __syncthreads();
#pragma unroll
        for (int u = t; u < Cn * KK; u += 256) {
            int cc = u >> 3, k = u & 7;
            papart[(size_t)g * (Cn * KK) + u] =
                red2[0][cc][k] + red2[1][cc][k] + red2[2][cc][k] + red2[3][cc][k];
        }
    }

    // ---------------- device-scope barrier ----------------
    __threadfence();          // release our global stores (device scope)
    __syncthreads();
    if (t == 0) {
        __hip_atomic_fetch_add(cnt, 1u, __ATOMIC_RELEASE, __HIP_MEMORY_SCOPE_AGENT);
        while (__hip_atomic_load(cnt, __ATOMIC_ACQUIRE, __HIP_MEMORY_SCOPE_AGENT)
               < (unsigned)NBLK)
            __builtin_amdgcn_s_sleep(2);
        // successful ACQUIRE load = acquire fence (L1/L2 invalidated, CU-wide)
    }
    __syncthreads();

    // ---------------- Phase B ----------------
    const int b = g >> 6, c = g & 63;

    if (w == 0) {                    // numerator merge: lane = pixel-block index
        const float* pp = papart + ((size_t)(b * 64 + lane) * Cn + c) * KK;
        float v[KK];
#pragma unroll
        for (int k = 0; k < KK; ++k) v[k] = pp[k];
#pragma unroll
        for (int k = 0; k < KK; ++k) {
            float sv = v[k];
#pragma unroll
            for (int o = 32; o; o >>= 1) sv += __shfl_xor(sv, o, 64);
            if (lane == 0) coef[k] = sv * inv_fact[k];
        }
    } else if (w == 1) {             // denominator merge
        const float* pq = pmpart + (size_t)(b * 64 + lane) * KK;
        float v[KK];
#pragma unroll
        for (int k = 1; k < KK; ++k) v[k] = pq[k];
#pragma unroll
        for (int k = 1; k < KK; ++k) {
            float sv = v[k];
#pragma unroll
            for (int o = 32; o; o >>= 1) sv += __shfl_xor(sv, o, 64);
            if (lane == 0) coef[KK + k] = sv * inv_fact[k];
        }
        if (lane == 0) coef[KK] = (float)HWn;   // sum_j m^0
    }
    __syncthreads();

    float cA[KK], cM[KK];
#pragma unroll
    for (int k = 0; k < KK; ++k) { cA[k] = coef[k]; cM[k] = coef[KK + k]; }

    const float4* mb4 = (const float4*)(m + b * HWn);
    float4* out4      = (float4*)(out + (size_t)(b * Cn + c) * HWn);
#pragma unroll
    for (int it = 0; it < 4; ++it) {          // 16 pixels / thread
        int u = it * 256 + t;
        float4 m4 = mb4[u];
        const float mm[4] = {m4.x, m4.y, m4.z, m4.w};
        float r[4];
#pragma unroll
        for (int e = 0; e < 4; ++e) {
            float s = mm[e];
            float num = cA[KK - 1], den = cM[KK - 1];
#pragma unroll
            for (int k = KK - 2; k >= 0; --k) {
                num = fmaf(num, s, cA[k]);
                den = fmaf(den, s, cM[k]);
            }
            r[e] = num * __builtin_amdgcn_rcpf(den);
        }
        out4[u] = make_float4(r[0], r[1], r[2], r[3]);
    }
}

extern "C" void kernel_launch(void* const* d_in, const int* in_sizes, int n_in,
                              void* d_out, int out_size, void* d_ws, size_t ws_size,
                              hipStream_t stream) {
    const float* x = (const float*)d_in[0];
    float* out = (float*)d_out;
    unsigned* cnt = (unsigned*)d_ws;           // 4 B counter (own 256 B line)
    float* m = (float*)d_ws + 64;              // 16384 floats
    float* pmpart = m + Bn * HWn;              // 256*8 floats
    float* papart = pmpart + NBLK * KK;        // 256*512 floats

    hipMemsetAsync(cnt, 0, 4, stream);         // reset barrier each call
    fused_all<<<NBLK, 256, 0, stream>>>(x, out, cnt, m, pmpart, papart);
}

// Round 8
// 16.192 us; speedup vs baseline: 3.0824x; 3.0824x over previous
//
#include <hip/hip_runtime.h>

// Problem constants (x: [4, 64, 64, 64] fp32)
#define Bn 4
#define Cn 64
#define HWn 4096
#define KK 8   // Taylor terms: |m_i*m_j| <= ~0.31 -> remainder 0.31^8/8! ~ 2e-9

typedef float f32x4 __attribute__((ext_vector_type(4)));   // native vec for NT builtins

// K1: grid 256 x 256. Block g: batch b=g>>6, 64 pixels at i0=(g&63)*64.
// Reads its 64ch x 64px chunk of x ONCE (non-temporal, coalesced), computes:
//   - m for its 64 pixels
//   - pmpart[g][k]    = sum_{slice} m^k            (k=1..KK-1, raw sums)
//   - papart[g][c][k] = sum_{slice} x[c][j]*m[j]^k (all 64 channels, raw sums)
__global__ __launch_bounds__(256) void mean_mom_kernel(const float* __restrict__ x,
                                                       float* __restrict__ m,
                                                       float* __restrict__ pmpart,
                                                       float* __restrict__ papart) {
    const int g = blockIdx.x;
    const int t = threadIdx.x, lane = t & 63, w = t >> 6;
    const int b = g >> 6;
    const int i0 = (g & 63) * 64;

    __shared__ float xs[64][65];      // [channel][pixel], +1 pad -> conflict-free
    __shared__ float redA[4][64];
    __shared__ float marr[64];
    __shared__ float red2[4][64][9];  // [quarter][channel][k], padded

    // Phase 1: coalesced chunk load (read-once -> non-temporal) + stash + partial sums
    const float* xb = x + ((size_t)(b * Cn + w * 16)) * HWn + i0 + lane;
    float s = 0.f;
#pragma unroll
    for (int cc = 0; cc < 16; ++cc) {
        float v = __builtin_nontemporal_load(&xb[(size_t)cc * HWn]);
        xs[w * 16 + cc][lane] = v;
        s += v;
    }
    redA[w][lane] = s;
    __syncthreads();

    if (w == 0) {
        float mv = (redA[0][lane] + redA[1][lane] + redA[2][lane] + redA[3][lane])
                   * (1.0f / Cn);
        m[b * HWn + i0 + lane] = mv;
        marr[lane] = mv;
        float q[KK];
        q[1] = mv;
#pragma unroll
        for (int k = 2; k < KK; ++k) q[k] = q[k - 1] * mv;
#pragma unroll
        for (int k = 1; k < KK; ++k) {
            float v = q[k];
#pragma unroll
            for (int o = 32; o; o >>= 1) v += __shfl_xor(v, o, 64);
            if (lane == 0) pmpart[g * KK + k] = v;   // raw sums
        }
    }
    __syncthreads();

    // Phase 2: numerator moments. thread -> channel c=lane, pixel-quarter qd=w.
    const int c = lane, qd = w;
    float pa[KK];
#pragma unroll
    for (int k = 0; k < KK; ++k) pa[k] = 0.f;
#pragma unroll
    for (int pp = 0; pp < 16; ++pp) {
        int pix = qd * 16 + pp;
        float mval = marr[pix];     // wave-broadcast
        float p = xs[c][pix];       // 2 lanes/bank via pad -> free
        pa[0] += p;
#pragma unroll
        for (int k = 1; k < KK; ++k) { p *= mval; pa[k] += p; }
    }
#pragma unroll
    for (int k = 0; k < KK; ++k) red2[qd][c][k] = pa[k];
    __syncthreads();

#pragma unroll
    for (int u = t; u < Cn * KK; u += 256) {
        int cc = u >> 3, k = u & 7;
        papart[(size_t)g * (Cn * KK) + u] =
            red2[0][cc][k] + red2[1][cc][k] + red2[2][cc][k] + red2[3][cc][k];
    }
}

// K2: grid 256 x 1024, barrier-free. Every wave redundantly merges the 64
// per-pixel-block partials (L1-hot, 4 KB) via butterfly shuffles — the full
// sums land in ALL lanes, so no LDS / __syncthreads is needed. Then Horner
// eval on this thread's 4 pixels + non-temporal store.
__global__ __launch_bounds__(1024) void eval_kernel(const float* __restrict__ m,
                                                    const float* __restrict__ pmpart,
                                                    const float* __restrict__ papart,
                                                    float* __restrict__ out) {
    const float inv_fact[KK] = {1.f, 1.f, 0.5f, 1.f / 6.f, 1.f / 24.f,
                                1.f / 120.f, 1.f / 720.f, 1.f / 5040.f};
    const int g = blockIdx.x, b = g >> 6, c = g & 63;
    const int t = threadIdx.x, lane = t & 63;

    const f32x4* mb4 = (const f32x4*)(m + b * HWn);
    f32x4 m4 = mb4[t];               // issue early; latency overlaps the merge

    // lane -> pixel-block index within batch b
    const f32x4* pp = (const f32x4*)(papart + ((size_t)(b * 64 + lane) * Cn + c) * KK);
    const f32x4* pq = (const f32x4*)(pmpart + (size_t)(b * 64 + lane) * KK);
    f32x4 a0 = pp[0], a1 = pp[1];
    f32x4 q0 = pq[0], q1 = pq[1];
    float vA[KK] = {a0.x, a0.y, a0.z, a0.w, a1.x, a1.y, a1.z, a1.w};
    float vM[KK] = {64.f, q0.y, q0.z, q0.w, q1.x, q1.y, q1.z, q1.w};  // k=0: 64 px/lane

    float cA[KK], cM[KK];
#pragma unroll
    for (int k = 0; k < KK; ++k) {
        float sa = vA[k], sm = vM[k];
#pragma unroll
        for (int o = 32; o; o >>= 1) {
            sa += __shfl_xor(sa, o, 64);
            sm += __shfl_xor(sm, o, 64);
        }
        cA[k] = sa * inv_fact[k];    // full sums in every lane
        cM[k] = sm * inv_fact[k];
    }

    const float mm[4] = {m4.x, m4.y, m4.z, m4.w};
    float r[4];
#pragma unroll
    for (int e = 0; e < 4; ++e) {
        float s = mm[e];
        float num = cA[KK - 1], den = cM[KK - 1];
#pragma unroll
        for (int k = KK - 2; k >= 0; --k) {
            num = fmaf(num, s, cA[k]);
            den = fmaf(den, s, cM[k]);
        }
        r[e] = num * __builtin_amdgcn_rcpf(den);
    }
    f32x4* out4 = (f32x4*)(out + (size_t)(b * Cn + c) * HWn);
    f32x4 rv = {r[0], r[1], r[2], r[3]};
    __builtin_nontemporal_store(rv, &out4[t]);
}

extern "C" void kernel_launch(void* const* d_in, const int* in_sizes, int n_in,
                              void* d_out, int out_size, void* d_ws, size_t ws_size,
                              hipStream_t stream) {
    const float* x = (const float*)d_in[0];
    float* out = (float*)d_out;
    float* m = (float*)d_ws;                   // 16384 floats = 64 KiB
    float* pmpart = m + Bn * HWn;              // 256*8 floats  = 8 KiB
    float* papart = pmpart + 256 * KK;         // 256*512 floats = 512 KiB

    mean_mom_kernel<<<Bn * 64, 256, 0, stream>>>(x, m, pmpart, papart);
    eval_kernel<<<Bn * Cn, 1024, 0, stream>>>(m, pmpart, papart, out);
}

// Round 9
// 14.186 us; speedup vs baseline: 3.5184x; 1.1414x over previous
//
#include <hip/hip_runtime.h>

// Problem constants (x: [4, 64, 64, 64] fp32)
#define Bn 4
#define Cn 64
#define HWn 4096
#define KK 8   // Taylor terms: |m_i*m_j| <= ~0.31 -> remainder 0.31^8/8! ~ 2e-9

typedef float f32x4 __attribute__((ext_vector_type(4)));   // native vec for NT builtins

// K1: grid 256 x 256. Block g: batch b=g>>6, 64 pixels at i0=(g&63)*64.
// Reads its 64ch x 64px chunk of x ONCE (NT, coalesced), computes:
//   - m for its 64 pixels
//   - pmpart[g][k]    = sum_{slice} m^k            (k=1..KK-1, raw sums)
//   - papart[g][c][k] = sum_{slice} x[c][j]*m[j]^k (all 64 channels, raw sums)
__global__ __launch_bounds__(256) void mean_mom_kernel(const float* __restrict__ x,
                                                       float* __restrict__ m,
                                                       float* __restrict__ pmpart,
                                                       float* __restrict__ papart) {
    const int g = blockIdx.x;
    const int t = threadIdx.x, lane = t & 63, w = t >> 6;
    const int b = g >> 6;
    const int i0 = (g & 63) * 64;

    __shared__ float xs[64][65];      // [channel][pixel], +1 pad -> conflict-free
    __shared__ float redA[4][64];
    __shared__ float marr[64];
    __shared__ float red2[4][64][9];  // [quarter][channel][k], padded

    // Phase 1: coalesced chunk load (read-once -> NT) + LDS stash + partial sums
    const float* xb = x + ((size_t)(b * Cn + w * 16)) * HWn + i0 + lane;
    float s = 0.f;
#pragma unroll
    for (int cc = 0; cc < 16; ++cc) {
        float v = __builtin_nontemporal_load(&xb[(size_t)cc * HWn]);
        xs[w * 16 + cc][lane] = v;
        s += v;
    }
    redA[w][lane] = s;
    __syncthreads();

    if (w == 0) {
        float mv = (redA[0][lane] + redA[1][lane] + redA[2][lane] + redA[3][lane])
                   * (1.0f / Cn);
        m[b * HWn + i0 + lane] = mv;
        marr[lane] = mv;
        float q[KK];
        q[1] = mv;
#pragma unroll
        for (int k = 2; k < KK; ++k) q[k] = q[k - 1] * mv;
#pragma unroll
        for (int k = 1; k < KK; ++k) {
            float v = q[k];
#pragma unroll
            for (int o = 32; o; o >>= 1) v += __shfl_xor(v, o, 64);
            if (lane == 0) pmpart[g * KK + k] = v;   // raw sums
        }
    }
    __syncthreads();

    // Phase 2: numerator moments. thread -> channel c=lane, pixel-quarter qd=w.
    const int c = lane, qd = w;
    float pa[KK];
#pragma unroll
    for (int k = 0; k < KK; ++k) pa[k] = 0.f;
#pragma unroll
    for (int pp = 0; pp < 16; ++pp) {
        int pix = qd * 16 + pp;
        float mval = marr[pix];     // wave-broadcast
        float p = xs[c][pix];       // 2 lanes/bank via pad -> free
        pa[0] += p;
#pragma unroll
        for (int k = 1; k < KK; ++k) { p *= mval; pa[k] += p; }
    }
#pragma unroll
    for (int k = 0; k < KK; ++k) red2[qd][c][k] = pa[k];
    __syncthreads();

#pragma unroll
    for (int u = t; u < Cn * KK; u += 256) {
        int cc = u >> 3, k = u & 7;
        papart[(size_t)g * (Cn * KK) + u] =
            red2[0][cc][k] + red2[1][cc][k] + red2[2][cc][k] + red2[3][cc][k];
    }
}

// K2 (round-5 structure): grid 256 x 1024. Block (b,c): waves 0/1 merge the
// 64 per-pixel-block partials (L2-resident) into LDS, one barrier, then all
// threads Horner-eval their 4 pixels + NT store. No x reads.
__global__ __launch_bounds__(1024) void eval_kernel(const float* __restrict__ m,
                                                    const float* __restrict__ pmpart,
                                                    const float* __restrict__ papart,
                                                    float* __restrict__ out) {
    const float inv_fact[KK] = {1.f, 1.f, 0.5f, 1.f / 6.f, 1.f / 24.f,
                                1.f / 120.f, 1.f / 720.f, 1.f / 5040.f};
    const int g = blockIdx.x, b = g >> 6, c = g & 63;
    const int t = threadIdx.x, lane = t & 63, w = t >> 6;   // 16 waves

    __shared__ float coef[2 * KK];   // [0..KK)=A/k!, [KK..2KK)=M/k!

    const f32x4* mb4 = (const f32x4*)(m + b * HWn);
    f32x4 m4 = mb4[t];               // issue early; latency overlaps the merge

    if (w == 0) {                    // numerator merge: lane = pixel-block index
        const float* pp = papart + ((size_t)(b * 64 + lane) * Cn + c) * KK;
        float v[KK];
#pragma unroll
        for (int k = 0; k < KK; ++k) v[k] = pp[k];
#pragma unroll
        for (int k = 0; k < KK; ++k) {
            float sv = v[k];
#pragma unroll
            for (int o = 32; o; o >>= 1) sv += __shfl_xor(sv, o, 64);
            if (lane == 0) coef[k] = sv * inv_fact[k];
        }
    } else if (w == 1) {             // denominator merge
        const float* pq = pmpart + (size_t)(b * 64 + lane) * KK;
        float v[KK];
#pragma unroll
        for (int k = 1; k < KK; ++k) v[k] = pq[k];
#pragma unroll
        for (int k = 1; k < KK; ++k) {
            float sv = v[k];
#pragma unroll
            for (int o = 32; o; o >>= 1) sv += __shfl_xor(sv, o, 64);
            if (lane == 0) coef[KK + k] = sv * inv_fact[k];
        }
        if (lane == 0) coef[KK] = (float)HWn;   // sum_j m^0
    }
    __syncthreads();

    float cA[KK], cM[KK];
#pragma unroll
    for (int k = 0; k < KK; ++k) { cA[k] = coef[k]; cM[k] = coef[KK + k]; }

    const float mm[4] = {m4.x, m4.y, m4.z, m4.w};
    float r[4];
#pragma unroll
    for (int e = 0; e < 4; ++e) {
        float s = mm[e];
        float num = cA[KK - 1], den = cM[KK - 1];
#pragma unroll
        for (int k = KK - 2; k >= 0; --k) {
            num = fmaf(num, s, cA[k]);
            den = fmaf(den, s, cM[k]);
        }
        r[e] = num * __builtin_amdgcn_rcpf(den);
    }
    f32x4* out4 = (f32x4*)(out + (size_t)(b * Cn + c) * HWn);
    f32x4 rv = {r[0], r[1], r[2], r[3]};
    __builtin_nontemporal_store(rv, &out4[t]);
}

extern "C" void kernel_launch(void* const* d_in, const int* in_sizes, int n_in,
                              void* d_out, int out_size, void* d_ws, size_t ws_size,
                              hipStream_t stream) {
    const float* x = (const float*)d_in[0];
    float* out = (float*)d_out;
    float* m = (float*)d_ws;                   // 16384 floats = 64 KiB
    float* pmpart = m + Bn * HWn;              // 256*8 floats  = 8 KiB
    float* papart = pmpart + 256 * KK;         // 256*512 floats = 512 KiB

    mean_mom_kernel<<<Bn * 64, 256, 0, stream>>>(x, m, pmpart, papart);
    eval_kernel<<<Bn * Cn, 1024, 0, stream>>>(m, pmpart, papart, out);
}